// Round 21
// baseline (694.508 us; speedup 1.0000x reference)
//
#include <hip/hip_runtime.h>
#include <hip/hip_bf16.h>

typedef _Float16 f16;
typedef __attribute__((ext_vector_type(2)))  _Float16 h2;
typedef __attribute__((ext_vector_type(8)))  _Float16 f16x8;
typedef __attribute__((ext_vector_type(4)))  _Float16 f16x4;
typedef __attribute__((ext_vector_type(16))) float    f32x16;

#define HW16K 16384

__device__ __forceinline__ void gld16(const void* g, void* l) {
    __builtin_amdgcn_global_load_lds((const __attribute__((address_space(1))) void*)g,
                                     (__attribute__((address_space(3))) void*)l, 16, 0, 0);
}

// ---------------------------------------------------------------------------
// Implicit-GEMM 3x3 conv via v_mfma_f32_32x32x16_f16.
// Activations CHANNEL-16-TILED NHWC: [B][Ye][CiT][Xe][16ch] f16.
// Row-pairing: block computes output rows (y0, y0+DIL), NR=4 staged rows,
// y0 = (k/DIL)*2*DIL + k%DIL (bijective; = 2k at DIL=1).
// DEPTH=2 __syncthreads pipeline: stage kt+1, compute kt, barrier.
// ROUND 21: XS=1 x-split for Co=128 layers — 1024 blocks of 2 rows x 64 px
// (8 waves = 2 rows x 2 px-tiles x 2 co-slots, MFW=2). LDS 16.9KB ->
// 4 blocks/CU, 32 waves/CU (100% occ, was 50%). Staging/weight traffic
// ~unchanged; adjacent blocks are x-halves of one row-pair (L2-shared rows).
// XS=0 layers bit-identical to the r20 champion.
// ---------------------------------------------------------------------------
template <int DIL, int PXW, int MFW, int XS, int MODE>
__global__ __launch_bounds__(512, 4) void conv_mfma(
    const f16* __restrict__ in, int inYe, int inXe, int inCiT, int inPad,
    const f16* __restrict__ wp, const float* __restrict__ bias,
    f16* __restrict__ out, int outYe, int outXe, int outCoT, int outPad, int outCoOff,
    float* __restrict__ dout,
    int Ci16, int CoPad)
{
    constexpr int PX   = XS ? 64 : 128;        // pixels per block
    constexpr int Wext = PX + 2 * DIL;
    constexpr int NR   = 4;
    constexpr int CH   = NR * Wext * 2;        // 16B chunks per K-tile
    constexpr int CHB  = CH * 16;
    constexpr int TI   = (CH + 511) / 512;
    __shared__ __align__(16) char smem[2 * CHB];

    const int tid  = threadIdx.x;
    const int lane = tid & 63;
    const int wv   = tid >> 6;
    const int col  = lane & 31;
    const int hi   = lane >> 5;
    const int t    = wv >> 2;                  // output-row slot within block
    const int wq   = wv & 3;
    constexpr int CPW = XS ? 2 : PXW;          // co-slots per row-group
    const int pp   = wq / CPW;                 // px-group index
    const int c    = wq % CPW;                 // co-slot index
    const int cb0  = blockIdx.y * (32 * MFW * CPW);

    const int g  = blockIdx.x;                 // XCD-swizzled
    const int b  = g & 7;                      // one batch per XCD
    const int k2 = g >> 3;                     // [0,64) or [0,128)
    const int xh = XS ? (k2 & 1) : 0;          // x-half (consecutive = same rows)
    const int k  = XS ? (k2 >> 1) : k2;
    const int y0 = (k / DIL) * (2 * DIL) + (k % DIL);   // = 2k at DIL=1
    const int x0 = 64 * xh;

    const f16* inb = in + (size_t)b * inYe * inCiT * inXe * 16;

    auto stage = [&](int kt, int bufi) {
        char* sb = smem + bufi * CHB;
#pragma unroll
        for (int i = 0; i < TI; ++i) {
            int cc = i * 512 + tid;
            if (cc < CH) {
                int r   = cc / (Wext * 2);
                int rem = cc - r * (Wext * 2);
                int px = rem >> 1, half = rem & 1;
                int yin = y0 + (r - 1) * DIL;
                const f16* src = inb
                    + (((size_t)(yin + inPad) * inCiT + kt) * inXe + (inPad - DIL + x0 + px)) * 16
                    + half * 8;
                gld16(src, sb + cc * 16);
            }
        }
    };

    f32x16 acc[PXW][MFW] = {};

    stage(0, 0);
    __syncthreads();
    for (int kt = 0; kt < Ci16; ++kt) {
        if (kt + 1 < Ci16) stage(kt + 1, (kt + 1) & 1);
        const char* sb = smem + (kt & 1) * CHB;
        const f16* wkt = wp + (size_t)kt * 9 * CoPad * 16 + hi * 8;

        if constexpr (MFW == 1) {
            f16x8 wfr[9];
#pragma unroll
            for (int k9 = 0; k9 < 9; ++k9)
                wfr[k9] = *(const f16x8*)(wkt + (size_t)k9 * CoPad * 16 +
                                          (cb0 + 32 * c + col) * 16);
#pragma unroll
            for (int ky = 0; ky < 3; ++ky) {
#pragma unroll
                for (int kx = 0; kx < 3; ++kx) {
                    const int rrow = t + ky;
#pragma unroll
                    for (int p = 0; p < PXW; ++p) {
                        const f16x8 bfrag = *(const f16x8*)(sb +
                            ((rrow * Wext + 32 * (PXW * pp + p) + col + kx * DIL) * 32 + hi * 16));
                        acc[p][0] = __builtin_amdgcn_mfma_f32_32x32x16_f16(
                            wfr[ky * 3 + kx], bfrag, acc[p][0], 0, 0, 0);
                    }
                }
            }
        } else {
#pragma unroll
            for (int ky = 0; ky < 3; ++ky) {
#pragma unroll
                for (int kx = 0; kx < 3; ++kx) {
                    const int rrow = t + ky;
                    f16x8 bfr[PXW];
#pragma unroll
                    for (int p = 0; p < PXW; ++p)
                        bfr[p] = *(const f16x8*)(sb +
                            ((rrow * Wext + 32 * (PXW * pp + p) + col + kx * DIL) * 32 + hi * 16));
                    const f16* wtap = wkt + (size_t)(ky * 3 + kx) * CoPad * 16;
#pragma unroll
                    for (int m = 0; m < MFW; ++m) {
                        const f16x8 afrag =
                            *(const f16x8*)(wtap + (cb0 + 32 * (c * MFW + m) + col) * 16);
#pragma unroll
                        for (int p = 0; p < PXW; ++p)
                            acc[p][m] = __builtin_amdgcn_mfma_f32_32x32x16_f16(
                                afrag, bfr[p], acc[p][m], 0, 0, 0);
                    }
                }
            }
        }
        __syncthreads();
    }

    // ---- epilogue ----
    const int y = y0 + t * DIL;
    if constexpr (MODE == 0) {
        const size_t prow = (size_t)(b * outYe + (y + outPad)) * outCoT;
#pragma unroll
        for (int p = 0; p < PXW; ++p) {
            const int x = x0 + 32 * (PXW * pp + p) + col;
#pragma unroll
            for (int m = 0; m < MFW; ++m) {
#pragma unroll
                for (int eq = 0; eq < 4; ++eq) {
                    const int co = cb0 + 32 * (c * MFW + m) + 8 * eq + 4 * hi;
                    f16x4 h;
#pragma unroll
                    for (int s = 0; s < 4; ++s) {
                        float v = acc[p][m][4 * eq + s] + bias[co + s];
                        v = (v >= 0.f) ? v : 0.1f * v;
                        h[s] = (f16)v;
                    }
                    *(f16x4*)(out + ((prow + (co >> 4)) * outXe + (outPad + x)) * 16
                                  + (co & 15)) = h;
                }
            }
        }
    } else {
        if (hi == 0) {
            const int x = x0 + 32 * pp + col;
#pragma unroll
            for (int s = 0; s < 2; ++s) {
                float v = acc[0][0][s] + bias[s];
                const size_t oi = (((size_t)b * 2 + s) * 128 + y) * 128 + x;
                if constexpr (MODE == 1) {
                    dout[oi] = v;
                    const int ch = outCoOff + s;
                    const size_t prow = (size_t)(b * outYe + (y + outPad)) * outCoT;
                    out[((prow + (ch >> 4)) * outXe + (outPad + x)) * 16 + (ch & 15)] = (f16)v;
                } else {
                    v = (v >= 0.f) ? v : 0.1f * v;
                    dout[oi] += v;
                }
            }
        }
    }
}

// ---------------------------------------------------------------------------
// Correlation (r14 champion): all 9 dy per block, acc[9][9] deep-ILP single
// pass (minimal FETCH ~35MB). Channel-pair layouts, v_dot2_f32_f16, scalar
// 4B loads, x = lane dim. Writes f16 into IN0 channels 128..208 (cit-tiled).
// ---------------------------------------------------------------------------
__global__ __launch_bounds__(256, 2) void corr_k(const h2* __restrict__ px1,
                                                 const h2* __restrict__ px2,
                                                 f16* __restrict__ in0) {
    const int g = blockIdx.x;                  // bijective XCD swizzle
    const int n = (g & 7) * 64 + (g >> 3);
    const int b = n >> 6;
    const int x = threadIdx.x & 127;
    const int y = (n & 63) * 2 + (threadIdx.x >> 7);

    const h2* p1  = px1 + (size_t)b * 64 * HW16K + y * 128 + x;
    const h2* p2b = px2 + (size_t)b * 64 * 18496 + (size_t)y * 136 + x;

    float acc[9][9] = {};
    for (int cp = 0; cp < 64; ++cp) {
        const h2 v1 = p1[(size_t)cp * HW16K];
        const h2* base = p2b + (size_t)cp * 18496;
#pragma unroll
        for (int j = 0; j < 9; ++j) {
            const h2* row = base + j * 136;
#pragma unroll
            for (int d = 0; d < 9; ++d)
                acc[j][d] = __builtin_amdgcn_fdot2(v1, row[d], acc[j][d], false);
        }
    }
    const size_t prow = (size_t)(b * 130 + (y + 1)) * 14;
#pragma unroll
    for (int j = 0; j < 9; ++j)
#pragma unroll
        for (int d = 0; d < 9; ++d) {
            const int o = j * 9 + d;
            in0[((prow + 8 + (o >> 4)) * 130 + (x + 1)) * 16 + (o & 15)] =
                (f16)(acc[j][d] * (1.f / 128.f));
        }
}

// x1 fp32 NCHW -> IN0 (cit-tiled) ch0..127 AND PX1 channel-pair layout
__global__ __launch_bounds__(256) void x1pack(const float* __restrict__ x1,
                                              f16* __restrict__ in0,
                                              h2* __restrict__ px1) {
    const int x = threadIdx.x & 127;
    const int y = blockIdx.x * 2 + (threadIdx.x >> 7);
    const int b = blockIdx.z;
    const float* p1 = x1 + (size_t)b * 128 * HW16K + y * 128 + x;
    h2* q = px1 + (size_t)b * 64 * HW16K + y * 128 + x;
    const size_t prow = (size_t)(b * 130 + (y + 1)) * 14;
    for (int cp = 0; cp < 64; ++cp) {
        const float a0 = p1[(2 * cp) * HW16K];
        const float a1 = p1[(2 * cp + 1) * HW16K];
        h2 v; v[0] = (f16)a0; v[1] = (f16)a1;
        q[(size_t)cp * HW16K] = v;
        const int ch = 2 * cp;
        *(h2*)(in0 + ((prow + (ch >> 4)) * 130 + (x + 1)) * 16 + (ch & 15)) = v;
    }
}

// x2 fp32 NCHW -> PX2 padded channel-pair layout (writes zeros in border)
__global__ __launch_bounds__(256) void x2pack(const float* __restrict__ x2,
                                              h2* __restrict__ px2) {
    const int cell = blockIdx.x * 256 + threadIdx.x;   // over 136x136
    if (cell >= 136 * 136) return;
    const int yp = cell / 136, xp = cell - yp * 136;
    const int cp = blockIdx.y, b = blockIdx.z;
    h2 v; v[0] = (f16)0.f; v[1] = (f16)0.f;
    const int yy = yp - 4, xx = xp - 4;
    if ((unsigned)yy < 128u && (unsigned)xx < 128u) {
        const float* p = x2 + (size_t)b * 128 * HW16K + (2 * cp) * HW16K + yy * 128 + xx;
        v[0] = (f16)p[0];
        v[1] = (f16)p[HW16K];
    }
    px2[((size_t)(b * 64 + cp) * 136 + yp) * 136 + xp] = v;
}

// fused: zero spatial borders of all 4 cit-tiled buffers (blockIdx.y selects)
struct ZB { f16* p[4]; int Ye[4], Xe[4], CiT[4], pad[4]; };
__global__ void zero_all(ZB z) {
    const int bi = blockIdx.y;
    const int Ye = z.Ye[bi], Xe = z.Xe[bi], CiT = z.CiT[bi], pad = z.pad[bi];
    const int cell = blockIdx.x * 256 + threadIdx.x;
    if (cell >= Ye * Xe) return;
    const int yy = cell / Xe, xx = cell - yy * Xe;
    if (yy >= pad && yy < Ye - pad && xx >= pad && xx < Xe - pad) return;
    f16x8 zz = {};
    for (int ct = 0; ct < CiT; ++ct) {
        f16* p = z.p[bi] + (((size_t)(blockIdx.z * Ye + yy) * CiT + ct) * Xe + xx) * 16;
        *(f16x8*)(p) = zz;
        *(f16x8*)(p + 8) = zz;
    }
}

// all 13 weight tensors: fp32 OIHW -> f16 [kt][tap][CoPad][16], zero-padded
struct PPA {
    const float* src[13];
    f16* dst[13];
    int Co[13], Ci[13], CoPad[13], CiPad[13];
};
__global__ void prepack_all(PPA a) {
    const int l = blockIdx.z;
    const int CoPad = a.CoPad[l], CiPad = a.CiPad[l];
    const int total = 9 * CoPad * CiPad;
    const int i = blockIdx.x * 256 + threadIdx.x;
    if (i >= total) return;
    const int k  = i / (CoPad * CiPad);
    const int r  = i - k * CoPad * CiPad;
    const int co = r / CiPad;
    const int ci = r - co * CiPad;
    f16 v = (f16)0.f;
    if (co < a.Co[l] && ci < a.Ci[l])
        v = (f16)a.src[l][((size_t)co * a.Ci[l] + ci) * 9 + k];
    const int kt = ci >> 4, cin = ci & 15;
    a.dst[l][(((size_t)kt * 9 + k) * CoPad + co) * 16 + cin] = v;
}

extern "C" void kernel_launch(void* const* d_in, const int* in_sizes, int n_in,
                              void* d_out, int out_size, void* d_ws, size_t ws_size,
                              hipStream_t stream) {
    const float* x1 = (const float*)d_in[0];
    const float* x2 = (const float*)d_in[1];
    const float* W[13]  = {(const float*)d_in[2],  (const float*)d_in[4],  (const float*)d_in[6],
                           (const float*)d_in[8],  (const float*)d_in[10], (const float*)d_in[12],
                           (const float*)d_in[14], (const float*)d_in[16], (const float*)d_in[18],
                           (const float*)d_in[20], (const float*)d_in[22], (const float*)d_in[24],
                           (const float*)d_in[26]};
    const float* Bs[13] = {(const float*)d_in[3],  (const float*)d_in[5],  (const float*)d_in[7],
                           (const float*)d_in[9],  (const float*)d_in[11], (const float*)d_in[13],
                           (const float*)d_in[15], (const float*)d_in[17], (const float*)d_in[19],
                           (const float*)d_in[21], (const float*)d_in[23], (const float*)d_in[25],
                           (const float*)d_in[27]};
    float* outp = (float*)d_out;

    // ---- workspace layout (bytes) ----  (cit-tiled)
    char* ws = (char*)d_ws;
    f16* IN0 = (f16*)(ws);                       // [8][130][14][130][16] = 60,569,600 B
    f16* P   = (f16*)(ws + 60569600);            // [8][144][8][144][16]  = 42,467,328 B
    f16* Q   = (f16*)(ws + 103036928);           // [8][160][8][160][16]  = 52,428,800 B
    f16* CC  = (f16*)(ws + 155465728);           // [8][130][4][130][16]  = 17,305,600 B
    char* WPB = ws + 172771328;
    // PX1/PX2 alias P/Q: consumed by corr BEFORE any conv writes P/Q.
    h2* PX1 = (h2*)P;
    h2* PX2 = (h2*)Q;

    // per-layer: {Co, Ci, CoPad, CiPad}
    const int LC[13][4] = {
        {128, 209, 128, 224}, {128, 128, 128, 128}, {96, 128, 96, 128},
        {64, 96, 64, 96},     {32, 64, 32, 64},     {2, 32, 32, 32},
        {128, 34, 128, 64},   {128, 128, 128, 128}, {128, 128, 128, 128},
        {96, 128, 96, 128},   {64, 96, 64, 96},     {32, 64, 32, 64},
        {2, 32, 32, 32}};
    f16* wpp[13];
    PPA pa;
    {
        size_t off = 0;
        for (int l = 0; l < 13; ++l) {
            wpp[l] = (f16*)(WPB + off);
            off += (size_t)9 * LC[l][2] * LC[l][3] * 2;
            pa.src[l] = W[l]; pa.dst[l] = wpp[l];
            pa.Co[l] = LC[l][0]; pa.Ci[l] = LC[l][1];
            pa.CoPad[l] = LC[l][2]; pa.CiPad[l] = LC[l][3];
        }
    }

    const dim3 blk(256, 1, 1);
    const dim3 blk512(512, 1, 1);

    // weights (single fused launch)
    prepack_all<<<dim3(1008, 1, 13), blk, 0, stream>>>(pa);

    // pack inputs + correlation
    x1pack<<<dim3(64, 1, 8), blk, 0, stream>>>(x1, IN0, PX1);
    x2pack<<<dim3(73, 64, 8), blk, 0, stream>>>(x2, PX2);
    corr_k<<<dim3(512, 1, 1), blk, 0, stream>>>(PX1, PX2, IN0);

    // PX1/PX2 dead -> zero ALL borders in one launch
    ZB zb;
    zb.p[0] = IN0; zb.Ye[0] = 130; zb.Xe[0] = 130; zb.CiT[0] = 14; zb.pad[0] = 1;
    zb.p[1] = CC;  zb.Ye[1] = 130; zb.Xe[1] = 130; zb.CiT[1] = 4;  zb.pad[1] = 1;
    zb.p[2] = P;   zb.Ye[2] = 144; zb.Xe[2] = 144; zb.CiT[2] = 8;  zb.pad[2] = 8;
    zb.p[3] = Q;   zb.Ye[3] = 160; zb.Xe[3] = 160; zb.CiT[3] = 8;  zb.pad[3] = 16;
    zero_all<<<dim3(100, 4, 8), blk, 0, stream>>>(zb);

    // ---- flow estimator ----
    conv_mfma<1, 1, 2, 1, 0><<<dim3(1024, 1, 1), blk512, 0, stream>>>(IN0, 130, 130, 14, 1, wpp[0], Bs[0],
                                                  P, 144, 144, 8, 8, 0, nullptr, 14, 128);
    conv_mfma<1, 1, 2, 1, 0><<<dim3(1024, 1, 1), blk512, 0, stream>>>(P, 144, 144, 8, 8, wpp[1], Bs[1],
                                                  Q, 160, 160, 8, 16, 0, nullptr, 8, 128);
    conv_mfma<1, 1, 3, 0, 0><<<dim3(512, 1, 1), blk512, 0, stream>>>(Q, 160, 160, 8, 16, wpp[2], Bs[2],
                                                  P, 144, 144, 8, 8, 0, nullptr, 8, 96);
    conv_mfma<1, 1, 2, 0, 0><<<dim3(512, 1, 1), blk512, 0, stream>>>(P, 144, 144, 8, 8, wpp[3], Bs[3],
                                                  Q, 160, 160, 8, 16, 0, nullptr, 6, 64);
    conv_mfma<1, 1, 1, 0, 0><<<dim3(512, 1, 1), blk512, 0, stream>>>(Q, 160, 160, 8, 16, wpp[4], Bs[4],
                                                  CC, 130, 130, 4, 1, 0, nullptr, 4, 32);
    // flow head: reads CC ch0..31, writes d_out fp32 + CC ch32/33
    conv_mfma<1, 1, 1, 0, 1><<<dim3(512, 1, 1), blk512, 0, stream>>>(CC, 130, 130, 4, 1, wpp[5], Bs[5],
                                                  CC, 130, 130, 4, 1, 32, outp, 2, 32);
    // ---- context network ----
    conv_mfma<1, 1, 2, 1, 0><<<dim3(1024, 1, 1), blk512, 0, stream>>>(CC, 130, 130, 4, 1, wpp[6], Bs[6],
                                                  P, 144, 144, 8, 8, 0, nullptr, 4, 128);
    conv_mfma<2, 1, 2, 1, 0><<<dim3(1024, 1, 1), blk512, 0, stream>>>(P, 144, 144, 8, 8, wpp[7], Bs[7],
                                                  Q, 160, 160, 8, 16, 0, nullptr, 8, 128);
    conv_mfma<4, 1, 2, 1, 0><<<dim3(1024, 1, 1), blk512, 0, stream>>>(Q, 160, 160, 8, 16, wpp[8], Bs[8],
                                                  P, 144, 144, 8, 8, 0, nullptr, 8, 128);
    conv_mfma<8, 1, 3, 0, 0><<<dim3(512, 1, 1), blk512, 0, stream>>>(P, 144, 144, 8, 8, wpp[9], Bs[9],
                                                  Q, 160, 160, 8, 16, 0, nullptr, 8, 96);
    conv_mfma<16, 1, 2, 0, 0><<<dim3(512, 1, 1), blk512, 0, stream>>>(Q, 160, 160, 8, 16, wpp[10], Bs[10],
                                                   P, 144, 144, 8, 8, 0, nullptr, 6, 64);
    conv_mfma<1, 1, 1, 0, 0><<<dim3(512, 1, 1), blk512, 0, stream>>>(P, 144, 144, 8, 8, wpp[11], Bs[11],
                                                  Q, 160, 160, 8, 16, 0, nullptr, 4, 32);
    // final: 32->2, leaky, += flo (d_out)
    conv_mfma<1, 1, 1, 0, 2><<<dim3(512, 1, 1), blk512, 0, stream>>>(Q, 160, 160, 8, 16, wpp[12], Bs[12],
                                                  nullptr, 0, 0, 0, 0, 0, outp, 2, 32);
}

// Round 22
// 608.137 us; speedup vs baseline: 1.1420x; 1.1420x over previous
//
#include <hip/hip_runtime.h>
#include <hip/hip_bf16.h>

typedef _Float16 f16;
typedef __attribute__((ext_vector_type(2)))  _Float16 h2;
typedef __attribute__((ext_vector_type(8)))  _Float16 f16x8;
typedef __attribute__((ext_vector_type(4)))  _Float16 f16x4;
typedef __attribute__((ext_vector_type(16))) float    f32x16;

#define HW16K 16384

__device__ __forceinline__ void gld16(const void* g, void* l) {
    __builtin_amdgcn_global_load_lds((const __attribute__((address_space(1))) void*)g,
                                     (__attribute__((address_space(3))) void*)l, 16, 0, 0);
}

// ---------------------------------------------------------------------------
// Implicit-GEMM 3x3 conv via v_mfma_f32_32x32x16_f16.  (r20 champion, final)
// Activations CHANNEL-16-TILED NHWC: [B][Ye][CiT][Xe][16ch] f16.
// Row-pairing: block computes output rows (y0, y0+DIL), NR=4 staged rows,
// y0 = (k/DIL)*2*DIL + k%DIL (bijective; = 2k at DIL=1).
// DEPTH=2 __syncthreads pipeline: stage kt+1, compute kt, barrier.
// Block 512 (8 waves) = 2 rows x 128 px x (32*PXW*MFW) co.
// ---------------------------------------------------------------------------
template <int DIL, int PXW, int MFW, int MODE>
__global__ __launch_bounds__(512, 4) void conv_mfma(
    const f16* __restrict__ in, int inYe, int inXe, int inCiT, int inPad,
    const f16* __restrict__ wp, const float* __restrict__ bias,
    f16* __restrict__ out, int outYe, int outXe, int outCoT, int outPad, int outCoOff,
    float* __restrict__ dout,
    int Ci16, int CoPad)
{
    constexpr int Wext = 128 + 2 * DIL;
    constexpr int NR   = 4;
    constexpr int CH   = NR * Wext * 2;        // 16B chunks per K-tile
    constexpr int CHB  = CH * 16;
    constexpr int TI   = (CH + 511) / 512;
    __shared__ __align__(16) char smem[2 * CHB];

    const int tid  = threadIdx.x;
    const int lane = tid & 63;
    const int wv   = tid >> 6;
    const int col  = lane & 31;
    const int hi   = lane >> 5;
    const int t    = wv >> 2;                  // output-row slot within block
    const int wq   = wv & 3;
    constexpr int CPW = PXW;                   // co-slots per row-group
    const int pp   = wq / CPW;                 // px-group index
    const int c    = wq % CPW;                 // co-slot index
    const int cb0  = blockIdx.y * (32 * PXW * MFW);

    const int g  = blockIdx.x;                 // XCD-swizzled (b, ychunk)
    const int n  = (g & 7) * 64 + (g >> 3);
    const int b  = n >> 6;
    const int k  = n & 63;
    const int y0 = (k / DIL) * (2 * DIL) + (k % DIL);   // = 2k at DIL=1

    const f16* inb = in + (size_t)b * inYe * inCiT * inXe * 16;

    auto stage = [&](int kt, int bufi) {
        char* sb = smem + bufi * CHB;
#pragma unroll
        for (int i = 0; i < TI; ++i) {
            int cc = i * 512 + tid;
            if (cc < CH) {
                int r   = cc / (Wext * 2);
                int rem = cc - r * (Wext * 2);
                int px = rem >> 1, half = rem & 1;
                int yin = y0 + (r - 1) * DIL;
                const f16* src = inb
                    + (((size_t)(yin + inPad) * inCiT + kt) * inXe + (inPad - DIL + px)) * 16
                    + half * 8;
                gld16(src, sb + cc * 16);
            }
        }
    };

    f32x16 acc[PXW][MFW] = {};

    stage(0, 0);
    __syncthreads();
    for (int kt = 0; kt < Ci16; ++kt) {
        if (kt + 1 < Ci16) stage(kt + 1, (kt + 1) & 1);
        const char* sb = smem + (kt & 1) * CHB;
        const f16* wkt = wp + (size_t)kt * 9 * CoPad * 16 + hi * 8;

        if constexpr (MFW == 1) {
            f16x8 wfr[9];
#pragma unroll
            for (int k9 = 0; k9 < 9; ++k9)
                wfr[k9] = *(const f16x8*)(wkt + (size_t)k9 * CoPad * 16 +
                                          (cb0 + 32 * c + col) * 16);
#pragma unroll
            for (int ky = 0; ky < 3; ++ky) {
#pragma unroll
                for (int kx = 0; kx < 3; ++kx) {
                    const int rrow = t + ky;
#pragma unroll
                    for (int p = 0; p < PXW; ++p) {
                        const f16x8 bfrag = *(const f16x8*)(sb +
                            ((rrow * Wext + 32 * (PXW * pp + p) + col + kx * DIL) * 32 + hi * 16));
                        acc[p][0] = __builtin_amdgcn_mfma_f32_32x32x16_f16(
                            wfr[ky * 3 + kx], bfrag, acc[p][0], 0, 0, 0);
                    }
                }
            }
        } else {
#pragma unroll
            for (int ky = 0; ky < 3; ++ky) {
#pragma unroll
                for (int kx = 0; kx < 3; ++kx) {
                    const int rrow = t + ky;
                    f16x8 bfr[PXW];
#pragma unroll
                    for (int p = 0; p < PXW; ++p)
                        bfr[p] = *(const f16x8*)(sb +
                            ((rrow * Wext + 32 * (PXW * pp + p) + col + kx * DIL) * 32 + hi * 16));
                    const f16* wtap = wkt + (size_t)(ky * 3 + kx) * CoPad * 16;
#pragma unroll
                    for (int m = 0; m < MFW; ++m) {
                        const f16x8 afrag =
                            *(const f16x8*)(wtap + (cb0 + 32 * (c * MFW + m) + col) * 16);
#pragma unroll
                        for (int p = 0; p < PXW; ++p)
                            acc[p][m] = __builtin_amdgcn_mfma_f32_32x32x16_f16(
                                afrag, bfr[p], acc[p][m], 0, 0, 0);
                    }
                }
            }
        }
        __syncthreads();
    }

    // ---- epilogue ----
    const int y = y0 + t * DIL;
    if constexpr (MODE == 0) {
        const size_t prow = (size_t)(b * outYe + (y + outPad)) * outCoT;
#pragma unroll
        for (int p = 0; p < PXW; ++p) {
            const int x = 32 * (PXW * pp + p) + col;
#pragma unroll
            for (int m = 0; m < MFW; ++m) {
#pragma unroll
                for (int eq = 0; eq < 4; ++eq) {
                    const int co = cb0 + 32 * (c * MFW + m) + 8 * eq + 4 * hi;
                    f16x4 h;
#pragma unroll
                    for (int s = 0; s < 4; ++s) {
                        float v = acc[p][m][4 * eq + s] + bias[co + s];
                        v = (v >= 0.f) ? v : 0.1f * v;
                        h[s] = (f16)v;
                    }
                    *(f16x4*)(out + ((prow + (co >> 4)) * outXe + (outPad + x)) * 16
                                  + (co & 15)) = h;
                }
            }
        }
    } else {
        if (hi == 0) {
            const int x = 32 * pp + col;
#pragma unroll
            for (int s = 0; s < 2; ++s) {
                float v = acc[0][0][s] + bias[s];
                const size_t oi = (((size_t)b * 2 + s) * 128 + y) * 128 + x;
                if constexpr (MODE == 1) {
                    dout[oi] = v;
                    const int ch = outCoOff + s;
                    const size_t prow = (size_t)(b * outYe + (y + outPad)) * outCoT;
                    out[((prow + (ch >> 4)) * outXe + (outPad + x)) * 16 + (ch & 15)] = (f16)v;
                } else {
                    v = (v >= 0.f) ? v : 0.1f * v;
                    dout[oi] += v;
                }
            }
        }
    }
}

// ---------------------------------------------------------------------------
// Correlation (r14 champion): all 9 dy per block, acc[9][9] deep-ILP single
// pass (minimal FETCH ~35MB, 88us measured). Channel-pair layouts,
// v_dot2_f32_f16, scalar 4B loads, x = lane dim.
// Writes f16 into IN0 channels 128..208 (cit-tiled layout).
// ---------------------------------------------------------------------------
__global__ __launch_bounds__(256, 2) void corr_k(const h2* __restrict__ px1,
                                                 const h2* __restrict__ px2,
                                                 f16* __restrict__ in0) {
    const int g = blockIdx.x;                  // bijective XCD swizzle
    const int n = (g & 7) * 64 + (g >> 3);
    const int b = n >> 6;
    const int x = threadIdx.x & 127;
    const int y = (n & 63) * 2 + (threadIdx.x >> 7);

    const h2* p1  = px1 + (size_t)b * 64 * HW16K + y * 128 + x;
    const h2* p2b = px2 + (size_t)b * 64 * 18496 + (size_t)y * 136 + x;

    float acc[9][9] = {};
    for (int cp = 0; cp < 64; ++cp) {
        const h2 v1 = p1[(size_t)cp * HW16K];
        const h2* base = p2b + (size_t)cp * 18496;
#pragma unroll
        for (int j = 0; j < 9; ++j) {
            const h2* row = base + j * 136;
#pragma unroll
            for (int d = 0; d < 9; ++d)
                acc[j][d] = __builtin_amdgcn_fdot2(v1, row[d], acc[j][d], false);
        }
    }
    const size_t prow = (size_t)(b * 130 + (y + 1)) * 14;
#pragma unroll
    for (int j = 0; j < 9; ++j)
#pragma unroll
        for (int d = 0; d < 9; ++d) {
            const int o = j * 9 + d;
            in0[((prow + 8 + (o >> 4)) * 130 + (x + 1)) * 16 + (o & 15)] =
                (f16)(acc[j][d] * (1.f / 128.f));
        }
}

// x1 fp32 NCHW -> IN0 (cit-tiled) ch0..127 AND PX1 channel-pair layout
__global__ __launch_bounds__(256) void x1pack(const float* __restrict__ x1,
                                              f16* __restrict__ in0,
                                              h2* __restrict__ px1) {
    const int x = threadIdx.x & 127;
    const int y = blockIdx.x * 2 + (threadIdx.x >> 7);
    const int b = blockIdx.z;
    const float* p1 = x1 + (size_t)b * 128 * HW16K + y * 128 + x;
    h2* q = px1 + (size_t)b * 64 * HW16K + y * 128 + x;
    const size_t prow = (size_t)(b * 130 + (y + 1)) * 14;
    for (int cp = 0; cp < 64; ++cp) {
        const float a0 = p1[(2 * cp) * HW16K];
        const float a1 = p1[(2 * cp + 1) * HW16K];
        h2 v; v[0] = (f16)a0; v[1] = (f16)a1;
        q[(size_t)cp * HW16K] = v;
        const int ch = 2 * cp;
        *(h2*)(in0 + ((prow + (ch >> 4)) * 130 + (x + 1)) * 16 + (ch & 15)) = v;
    }
}

// x2 fp32 NCHW -> PX2 padded channel-pair layout (writes zeros in border)
__global__ __launch_bounds__(256) void x2pack(const float* __restrict__ x2,
                                              h2* __restrict__ px2) {
    const int cell = blockIdx.x * 256 + threadIdx.x;   // over 136x136
    if (cell >= 136 * 136) return;
    const int yp = cell / 136, xp = cell - yp * 136;
    const int cp = blockIdx.y, b = blockIdx.z;
    h2 v; v[0] = (f16)0.f; v[1] = (f16)0.f;
    const int yy = yp - 4, xx = xp - 4;
    if ((unsigned)yy < 128u && (unsigned)xx < 128u) {
        const float* p = x2 + (size_t)b * 128 * HW16K + (2 * cp) * HW16K + yy * 128 + xx;
        v[0] = (f16)p[0];
        v[1] = (f16)p[HW16K];
    }
    px2[((size_t)(b * 64 + cp) * 136 + yp) * 136 + xp] = v;
}

// fused: zero spatial borders of all 4 cit-tiled buffers (blockIdx.y selects)
struct ZB { f16* p[4]; int Ye[4], Xe[4], CiT[4], pad[4]; };
__global__ void zero_all(ZB z) {
    const int bi = blockIdx.y;
    const int Ye = z.Ye[bi], Xe = z.Xe[bi], CiT = z.CiT[bi], pad = z.pad[bi];
    const int cell = blockIdx.x * 256 + threadIdx.x;
    if (cell >= Ye * Xe) return;
    const int yy = cell / Xe, xx = cell - yy * Xe;
    if (yy >= pad && yy < Ye - pad && xx >= pad && xx < Xe - pad) return;
    f16x8 zz = {};
    for (int ct = 0; ct < CiT; ++ct) {
        f16* p = z.p[bi] + (((size_t)(blockIdx.z * Ye + yy) * CiT + ct) * Xe + xx) * 16;
        *(f16x8*)(p) = zz;
        *(f16x8*)(p + 8) = zz;
    }
}

// all 13 weight tensors: fp32 OIHW -> f16 [kt][tap][CoPad][16], zero-padded
struct PPA {
    const float* src[13];
    f16* dst[13];
    int Co[13], Ci[13], CoPad[13], CiPad[13];
};
__global__ void prepack_all(PPA a) {
    const int l = blockIdx.z;
    const int CoPad = a.CoPad[l], CiPad = a.CiPad[l];
    const int total = 9 * CoPad * CiPad;
    const int i = blockIdx.x * 256 + threadIdx.x;
    if (i >= total) return;
    const int k  = i / (CoPad * CiPad);
    const int r  = i - k * CoPad * CiPad;
    const int co = r / CiPad;
    const int ci = r - co * CiPad;
    f16 v = (f16)0.f;
    if (co < a.Co[l] && ci < a.Ci[l])
        v = (f16)a.src[l][((size_t)co * a.Ci[l] + ci) * 9 + k];
    const int kt = ci >> 4, cin = ci & 15;
    a.dst[l][(((size_t)kt * 9 + k) * CoPad + co) * 16 + cin] = v;
}

extern "C" void kernel_launch(void* const* d_in, const int* in_sizes, int n_in,
                              void* d_out, int out_size, void* d_ws, size_t ws_size,
                              hipStream_t stream) {
    const float* x1 = (const float*)d_in[0];
    const float* x2 = (const float*)d_in[1];
    const float* W[13]  = {(const float*)d_in[2],  (const float*)d_in[4],  (const float*)d_in[6],
                           (const float*)d_in[8],  (const float*)d_in[10], (const float*)d_in[12],
                           (const float*)d_in[14], (const float*)d_in[16], (const float*)d_in[18],
                           (const float*)d_in[20], (const float*)d_in[22], (const float*)d_in[24],
                           (const float*)d_in[26]};
    const float* Bs[13] = {(const float*)d_in[3],  (const float*)d_in[5],  (const float*)d_in[7],
                           (const float*)d_in[9],  (const float*)d_in[11], (const float*)d_in[13],
                           (const float*)d_in[15], (const float*)d_in[17], (const float*)d_in[19],
                           (const float*)d_in[21], (const float*)d_in[23], (const float*)d_in[25],
                           (const float*)d_in[27]};
    float* outp = (float*)d_out;

    // ---- workspace layout (bytes) ----  (cit-tiled)
    char* ws = (char*)d_ws;
    f16* IN0 = (f16*)(ws);                       // [8][130][14][130][16] = 60,569,600 B
    f16* P   = (f16*)(ws + 60569600);            // [8][144][8][144][16]  = 42,467,328 B
    f16* Q   = (f16*)(ws + 103036928);           // [8][160][8][160][16]  = 52,428,800 B
    f16* CC  = (f16*)(ws + 155465728);           // [8][130][4][130][16]  = 17,305,600 B
    char* WPB = ws + 172771328;
    // PX1/PX2 alias P/Q: consumed by corr BEFORE any conv writes P/Q.
    h2* PX1 = (h2*)P;
    h2* PX2 = (h2*)Q;

    // per-layer: {Co, Ci, CoPad, CiPad}
    const int LC[13][4] = {
        {128, 209, 128, 224}, {128, 128, 128, 128}, {96, 128, 96, 128},
        {64, 96, 64, 96},     {32, 64, 32, 64},     {2, 32, 32, 32},
        {128, 34, 128, 64},   {128, 128, 128, 128}, {128, 128, 128, 128},
        {96, 128, 96, 128},   {64, 96, 64, 96},     {32, 64, 32, 64},
        {2, 32, 32, 32}};
    f16* wpp[13];
    PPA pa;
    {
        size_t off = 0;
        for (int l = 0; l < 13; ++l) {
            wpp[l] = (f16*)(WPB + off);
            off += (size_t)9 * LC[l][2] * LC[l][3] * 2;
            pa.src[l] = W[l]; pa.dst[l] = wpp[l];
            pa.Co[l] = LC[l][0]; pa.Ci[l] = LC[l][1];
            pa.CoPad[l] = LC[l][2]; pa.CiPad[l] = LC[l][3];
        }
    }

    const dim3 blk(256, 1, 1);
    const dim3 blk512(512, 1, 1);

    // weights (single fused launch)
    prepack_all<<<dim3(1008, 1, 13), blk, 0, stream>>>(pa);

    // pack inputs + correlation
    x1pack<<<dim3(64, 1, 8), blk, 0, stream>>>(x1, IN0, PX1);
    x2pack<<<dim3(73, 64, 8), blk, 0, stream>>>(x2, PX2);
    corr_k<<<dim3(512, 1, 1), blk, 0, stream>>>(PX1, PX2, IN0);

    // PX1/PX2 dead -> zero ALL borders in one launch
    ZB zb;
    zb.p[0] = IN0; zb.Ye[0] = 130; zb.Xe[0] = 130; zb.CiT[0] = 14; zb.pad[0] = 1;
    zb.p[1] = CC;  zb.Ye[1] = 130; zb.Xe[1] = 130; zb.CiT[1] = 4;  zb.pad[1] = 1;
    zb.p[2] = P;   zb.Ye[2] = 144; zb.Xe[2] = 144; zb.CiT[2] = 8;  zb.pad[2] = 8;
    zb.p[3] = Q;   zb.Ye[3] = 160; zb.Xe[3] = 160; zb.CiT[3] = 8;  zb.pad[3] = 16;
    zero_all<<<dim3(100, 4, 8), blk, 0, stream>>>(zb);

    // ---- flow estimator ----
    conv_mfma<1, 2, 2, 0><<<dim3(512, 1, 1), blk512, 0, stream>>>(IN0, 130, 130, 14, 1, wpp[0], Bs[0],
                                                  P, 144, 144, 8, 8, 0, nullptr, 14, 128);
    conv_mfma<1, 2, 2, 0><<<dim3(512, 1, 1), blk512, 0, stream>>>(P, 144, 144, 8, 8, wpp[1], Bs[1],
                                                  Q, 160, 160, 8, 16, 0, nullptr, 8, 128);
    conv_mfma<1, 1, 3, 0><<<dim3(512, 1, 1), blk512, 0, stream>>>(Q, 160, 160, 8, 16, wpp[2], Bs[2],
                                                  P, 144, 144, 8, 8, 0, nullptr, 8, 96);
    conv_mfma<1, 1, 2, 0><<<dim3(512, 1, 1), blk512, 0, stream>>>(P, 144, 144, 8, 8, wpp[3], Bs[3],
                                                  Q, 160, 160, 8, 16, 0, nullptr, 6, 64);
    conv_mfma<1, 1, 1, 0><<<dim3(512, 1, 1), blk512, 0, stream>>>(Q, 160, 160, 8, 16, wpp[4], Bs[4],
                                                  CC, 130, 130, 4, 1, 0, nullptr, 4, 32);
    // flow head: reads CC ch0..31, writes d_out fp32 + CC ch32/33
    conv_mfma<1, 1, 1, 1><<<dim3(512, 1, 1), blk512, 0, stream>>>(CC, 130, 130, 4, 1, wpp[5], Bs[5],
                                                  CC, 130, 130, 4, 1, 32, outp, 2, 32);
    // ---- context network ----
    conv_mfma<1, 2, 2, 0><<<dim3(512, 1, 1), blk512, 0, stream>>>(CC, 130, 130, 4, 1, wpp[6], Bs[6],
                                                  P, 144, 144, 8, 8, 0, nullptr, 4, 128);
    conv_mfma<2, 2, 2, 0><<<dim3(512, 1, 1), blk512, 0, stream>>>(P, 144, 144, 8, 8, wpp[7], Bs[7],
                                                  Q, 160, 160, 8, 16, 0, nullptr, 8, 128);
    conv_mfma<4, 2, 2, 0><<<dim3(512, 1, 1), blk512, 0, stream>>>(Q, 160, 160, 8, 16, wpp[8], Bs[8],
                                                  P, 144, 144, 8, 8, 0, nullptr, 8, 128);
    conv_mfma<8, 1, 3, 0><<<dim3(512, 1, 1), blk512, 0, stream>>>(P, 144, 144, 8, 8, wpp[9], Bs[9],
                                                  Q, 160, 160, 8, 16, 0, nullptr, 8, 96);
    conv_mfma<16, 1, 2, 0><<<dim3(512, 1, 1), blk512, 0, stream>>>(Q, 160, 160, 8, 16, wpp[10], Bs[10],
                                                   P, 144, 144, 8, 8, 0, nullptr, 6, 64);
    conv_mfma<1, 1, 1, 0><<<dim3(512, 1, 1), blk512, 0, stream>>>(P, 144, 144, 8, 8, wpp[11], Bs[11],
                                                  Q, 160, 160, 8, 16, 0, nullptr, 4, 32);
    // final: 32->2, leaky, += flo (d_out)
    conv_mfma<1, 1, 1, 2><<<dim3(512, 1, 1), blk512, 0, stream>>>(Q, 160, 160, 8, 16, wpp[12], Bs[12],
                                                  nullptr, 0, 0, 0, 0, 0, outp, 2, 32);
}